// Round 1
// 409.091 us; speedup vs baseline: 1.0413x; 1.0413x over previous
//
#include <hip/hip_runtime.h>

#define B_TOTAL 131072
#define KDIM    512
#define NDIM    100
#define NPAD    112      // 7 n-tiles of 16
#define NT      7        // n tiles per wave
#define NTERMS  7        // Taylor degree for expm (tail ~2e-9 even at 3sigma ||A||)
#define LSTRIDE 108      // LDS row stride in floats: 432B = 16B-aligned; epilogue
                         // writes 2-way bank conflict (free), A-reads 4-way (1.58x)

using bf16x8 = __attribute__((ext_vector_type(8))) short;
using f32x4  = __attribute__((ext_vector_type(4))) float;

// round-to-nearest-even fp32 -> bf16 (bit trick; NaN path irrelevant here)
__device__ __forceinline__ unsigned short f2bf(float x) {
    union { float f; unsigned u; } v; v.f = x;
    unsigned r = v.u + 0x7fffu + ((v.u >> 16) & 1u);
    return (unsigned short)(r >> 16);
}

// ---------------------------------------------------------------------------
// Kernel 0 (prep): btT[n][k] = bf16(basis[k][n]), n padded to 112 with zeros.
// 115 KB into d_ws; runs once per launch, L2-resident for the GEMM.
// ---------------------------------------------------------------------------
__global__ __launch_bounds__(256) void basis_prep_kernel(
    const float* __restrict__ basis, unsigned short* __restrict__ btT)
{
    const int idx = blockIdx.x * 256 + threadIdx.x;   // 0 .. 112*512-1
    const int n = idx >> 9;          // 0..111
    const int k = idx & 511;
    btT[idx] = (n < NDIM) ? f2bf(basis[(size_t)k * NDIM + n]) : (unsigned short)0;
}

// ---------------------------------------------------------------------------
// Fused kernel: lie_alg = z @ basis (bf16 MFMA, direct loads, no staging) ->
// LDS turn-around -> expm in place -> single global write of exp(lie_alg).
//
// Removes the 52MB write + 52MB strided re-read of lie_alg through HBM that
// the 2-kernel version paid, plus expm's 64-lines-per-instruction global
// access pattern (each lane's matrix now comes from LDS).
//
// Phase 1 (GEMM): each wave owns 32 rows x 112 cols, A-frags straight from z
// (fp32->bf16 pack in regs), B-frags from L2-resident btT. Epilogue lands in
// lds[lb][n], lb = local batch 0..127, n = flattened 10x10 element 0..99.
// Phase 2 (expm): 2 threads per matrix (t>>1), each computes 5 rows of
// exp(A) via degree-7 Taylor Horner. A[100] register-resident (elementwise
// constant-index copies from LDS -- keeps mem2reg happy, see R2 post-mortem).
// k-loop fully unrolled so 1/k constant-folds (no IEEE div chains).
// ---------------------------------------------------------------------------
__global__ __launch_bounds__(256, 2) void lie_fused(
    const float* __restrict__ z, const unsigned short* __restrict__ btT,
    float* __restrict__ out)
{
    __shared__ __align__(16) float lds[128 * LSTRIDE];   // 55296 B

    const int t    = threadIdx.x;
    const int wave = t >> 6;
    const int lane = t & 63;
    const int ln   = lane & 15;         // m (A) / n (B) index within 16-tile
    const int kq   = (lane >> 4) * 8;   // k sub-offset within 32-wide mfma step
    const int m0   = blockIdx.x * 128 + wave * 32;

    const float* zr0 = &z[(size_t)(m0 + ln) * KDIM + kq];
    const float* zr1 = zr0 + (size_t)16 * KDIM;
    const unsigned short* bp = &btT[(size_t)ln * KDIM + kq];

    f32x4 acc[2][NT];
#pragma unroll
    for (int mt = 0; mt < 2; ++mt)
#pragma unroll
        for (int nt = 0; nt < NT; ++nt)
            acc[mt][nt] = (f32x4){0.f, 0.f, 0.f, 0.f};

#pragma unroll 1
    for (int ks = 0; ks < KDIM; ks += 32) {
        const float4 va0 = *(const float4*)&zr0[ks];
        const float4 va1 = *(const float4*)&zr0[ks + 4];
        const float4 vb0 = *(const float4*)&zr1[ks];
        const float4 vb1 = *(const float4*)&zr1[ks + 4];

        bf16x8 a0, a1;
        a0[0] = f2bf(va0.x); a0[1] = f2bf(va0.y); a0[2] = f2bf(va0.z); a0[3] = f2bf(va0.w);
        a0[4] = f2bf(va1.x); a0[5] = f2bf(va1.y); a0[6] = f2bf(va1.z); a0[7] = f2bf(va1.w);
        a1[0] = f2bf(vb0.x); a1[1] = f2bf(vb0.y); a1[2] = f2bf(vb0.z); a1[3] = f2bf(vb0.w);
        a1[4] = f2bf(vb1.x); a1[5] = f2bf(vb1.y); a1[6] = f2bf(vb1.z); a1[7] = f2bf(vb1.w);

#pragma unroll
        for (int nt = 0; nt < NT; ++nt) {
            const bf16x8 bf = *(const bf16x8*)&bp[(size_t)nt * 16 * KDIM + ks];
            acc[0][nt] = __builtin_amdgcn_mfma_f32_16x16x32_bf16(a0, bf, acc[0][nt], 0, 0, 0);
            acc[1][nt] = __builtin_amdgcn_mfma_f32_16x16x32_bf16(a1, bf, acc[1][nt], 0, 0, 0);
        }
    }

    // epilogue -> LDS. C/D layout col=lane&15, row=(lane>>4)*4+reg (m89/m91).
    // lb = local batch row; n = matrix element index. Only n<100 kept.
    const int lb0 = wave * 32 + ((lane >> 4) << 2);
#pragma unroll
    for (int mt = 0; mt < 2; ++mt) {
#pragma unroll
        for (int nt = 0; nt < NT; ++nt) {
            const int n = nt * 16 + ln;
            if (n < NDIM) {
#pragma unroll
                for (int r = 0; r < 4; ++r)
                    lds[(lb0 + mt * 16 + r) * LSTRIDE + n] = acc[mt][nt][r];
            }
        }
    }

    __syncthreads();

    // ---------------- Phase 2: expm on the block's 128 matrices ------------
    const int mb   = t >> 1;       // matrix 0..127 (lane pairs broadcast-read)
    const int tpar = t & 1;        // which 5 rows of exp(A) this thread does
    const size_t gbase = ((size_t)blockIdx.x * 128 + mb) * NDIM;

    float A[100];
#pragma unroll
    for (int s = 0; s < 25; ++s) {
        const f32x4 v = *(const f32x4*)&lds[mb * LSTRIDE + s * 4];  // ds_read_b128
        A[s * 4 + 0] = v[0];
        A[s * 4 + 1] = v[1];
        A[s * 4 + 2] = v[2];
        A[s * 4 + 3] = v[3];
    }

#pragma unroll 1
    for (int ii = 0; ii < 5; ++ii) {
        const int i = tpar * 5 + ii;

        float e[10], u[10];
#pragma unroll
        for (int j = 0; j < 10; ++j) {
            e[j] = (j == i) ? 1.f : 0.f;
            u[j] = e[j];
        }

#pragma unroll
        for (int k = NTERMS; k >= 1; --k) {
            float tmp[10];
#pragma unroll
            for (int j = 0; j < 10; ++j) tmp[j] = 0.f;
#pragma unroll
            for (int m = 0; m < 10; ++m) {
                const float um = u[m];
#pragma unroll
                for (int j = 0; j < 10; ++j)
                    tmp[j] = fmaf(um, A[m * 10 + j], tmp[j]);
            }
            const float inv = 1.f / (float)k;   // k is a literal: folds at compile time
#pragma unroll
            for (int j = 0; j < 10; ++j)
                u[j] = fmaf(tmp[j], inv, e[j]);
        }

#pragma unroll
        for (int s = 0; s < 5; ++s) {
            float2 v2;
            v2.x = u[s * 2];
            v2.y = u[s * 2 + 1];
            *(float2*)&out[gbase + (size_t)i * 10 + s * 2] = v2;  // 8B-aligned
        }
    }
}

extern "C" void kernel_launch(void* const* d_in, const int* in_sizes, int n_in,
                              void* d_out, int out_size, void* d_ws, size_t ws_size,
                              hipStream_t stream)
{
    const float* z     = (const float*)d_in[0];
    const float* basis = (const float*)d_in[1];
    float* out         = (float*)d_out;
    unsigned short* btT = (unsigned short*)d_ws;   // 112*512*2 = 114688 B

    basis_prep_kernel<<<(NPAD * KDIM) / 256, 256, 0, stream>>>(basis, btT);
    lie_fused<<<B_TOTAL / 128, 256, 0, stream>>>(z, btT, out);
}